// Round 3
// baseline (32781.638 us; speedup 1.0000x reference)
//
#include <hip/hip_runtime.h>

typedef unsigned short u16;
typedef float f32x4 __attribute__((ext_vector_type(4)));
typedef short s16x8 __attribute__((ext_vector_type(8)));

#define B_ 64
#define T_ 512
#define I_ 512
#define H_ 1024
#define NBLK 64
#define NTHR 256
#define KC 128   // k-chunk for s / rs staging
#define KCX 64   // k-chunk for x / W staging

// workspace layout (bytes)
#define OFF_SCUR 1024                      // f32 [64][1024]   262144
#define OFF_RS   (OFF_SCUR + 262144)       // bf16 [64][1024]  131072
#define OFF_U    (OFF_RS + 131072)         // bf16 [3][1024][1024] 6291456
#define OFF_W    (OFF_U + 6291456)         // bf16 [3][1024][512]  3145728

__device__ __forceinline__ u16 f2bf(float f) {
  unsigned u = __float_as_uint(f);
  return (u16)((u + 0x7FFFu + ((u >> 16) & 1u)) >> 16);
}

__global__ void prep_kernel(const float* __restrict__ s0,
                            const float* __restrict__ Wz, const float* __restrict__ Wr,
                            const float* __restrict__ Ws, const float* __restrict__ Uz,
                            const float* __restrict__ Ur, const float* __restrict__ Us,
                            char* __restrict__ ws) {
  float* scur = (float*)(ws + OFF_SCUR);
  u16* ubf = (u16*)(ws + OFF_U);
  u16* wbf = (u16*)(ws + OFF_W);
  int tid = blockIdx.x * blockDim.x + threadIdx.x;
  int stride = gridDim.x * blockDim.x;
  for (int i = tid; i < B_ * H_; i += stride) scur[i] = s0[i];
  const int NU = H_ * H_;
  for (int i = tid; i < NU; i += stride) {
    ubf[i] = f2bf(Uz[i]);
    ubf[NU + i] = f2bf(Ur[i]);
    ubf[2 * NU + i] = f2bf(Us[i]);
  }
  const int NW = H_ * I_;
  for (int i = tid; i < NW; i += stride) {
    wbf[i] = f2bf(Wz[i]);
    wbf[NW + i] = f2bf(Wr[i]);
    wbf[2 * NW + i] = f2bf(Ws[i]);
  }
}

// sense-reversing grid barrier over NBLK blocks (agent scope, cross-XCD safe).
// Co-residency of all NBLK blocks is guaranteed by construction: 126KB LDS
// -> 1 block/CU, 64 blocks << 256 CUs, launched on an otherwise-idle device.
__device__ __forceinline__ void gbar(unsigned* cnt, unsigned* gen) {
  __builtin_amdgcn_fence(__ATOMIC_RELEASE, "agent");
  __syncthreads();
  if (threadIdx.x == 0) {
    unsigned g = __hip_atomic_load(gen, __ATOMIC_RELAXED, __HIP_MEMORY_SCOPE_AGENT);
    unsigned a = __hip_atomic_fetch_add(cnt, 1u, __ATOMIC_ACQ_REL, __HIP_MEMORY_SCOPE_AGENT);
    if (a == (unsigned)(NBLK - 1)) {
      __hip_atomic_store(cnt, 0u, __ATOMIC_RELAXED, __HIP_MEMORY_SCOPE_AGENT);
      __hip_atomic_fetch_add(gen, 1u, __ATOMIC_RELEASE, __HIP_MEMORY_SCOPE_AGENT);
    } else {
      while (__hip_atomic_load(gen, __ATOMIC_RELAXED, __HIP_MEMORY_SCOPE_AGENT) == g)
        __builtin_amdgcn_s_sleep(1);
    }
  }
  __syncthreads();
  __builtin_amdgcn_fence(__ATOMIC_ACQUIRE, "agent");
}

#define SWZ(row, byteInRow, rowShift) \
  (((((row) << (rowShift)) + (byteInRow))) ^ (((row) & 7) << 4))

__global__ __launch_bounds__(NTHR, 1) void scan_kernel(
    const float* __restrict__ x, const float* __restrict__ mask,
    const float* __restrict__ bz, const float* __restrict__ br,
    const float* __restrict__ bs, char* __restrict__ ws,
    float* __restrict__ out) {

  __shared__ u16 u_lds[3 * 16 * 1024];  // 96KB  U slices, row=(g*16+hi), 1024 k, swizzled
  __shared__ u16 st_a[64 * KC];         // 16KB  s / rs chunk
  __shared__ u16 st_x[64 * KCX];        // 8KB   x chunk
  __shared__ u16 st_w[48 * KCX];        // 6KB   W chunk (3 gates x 16 rows)

  float* scur = (float*)(ws + OFF_SCUR);
  u16* rsb = (u16*)(ws + OFF_RS);
  const u16* ubf = (const u16*)(ws + OFF_U);
  const u16* wbf = (const u16*)(ws + OFF_W);
  unsigned* cnt = (unsigned*)ws;
  unsigned* gen = (unsigned*)(ws + 256);

  const int tid = threadIdx.x;
  const int h0 = blockIdx.x * 16;
  const int lane = tid & 63;
  const int wave = tid >> 6;
  const int bm = wave << 4;       // m-tile (batch) base for this wave
  const int ln15 = lane & 15;
  const int kg = lane >> 4;
  const int h = h0 + ln15;

  // preload U slices into LDS (once per kernel, reused for 512 steps)
  for (int e = tid * 8; e < 3 * 16 * 1024; e += NTHR * 8) {
    int row = e >> 10;            // 0..47  (g*16 + hi)
    int k = e & 1023;
    int g = row >> 4, hi = row & 15;
    uint4 v = *(const uint4*)(ubf + ((g * H_ + h0 + hi) * H_ + k));
    *(uint4*)((char*)u_lds + SWZ(row, (k << 1), 11)) = v;
  }
  const float bzv = bz[h];
  const float brv = br[h];
  const float bsv = bs[h];
  __syncthreads();

  for (int t = 0; t < T_; ++t) {
    f32x4 accz = {0.f, 0.f, 0.f, 0.f}, accr = {0.f, 0.f, 0.f, 0.f};
    f32x4 apz = {0.f, 0.f, 0.f, 0.f}, apr = {0.f, 0.f, 0.f, 0.f}, aps = {0.f, 0.f, 0.f, 0.f};
    const float* xt = x + t * I_;

    // ---------------- phase 1: z, r (recurrent) + projections ----------------
    for (int kc = 0; kc < 8; ++kc) {
      const int k0 = kc * KC;     // s k-range
      const int kx0 = kc * KCX;   // x k-range
      // stage s chunk (f32 -> bf16, swizzled)
      #pragma unroll
      for (int e = tid * 4; e < 64 * KC; e += NTHR * 4) {
        int row = e >> 7, col = e & (KC - 1);
        float4 f = *(const float4*)(scur + row * H_ + k0 + col);
        ushort4 v;
        v.x = f2bf(f.x); v.y = f2bf(f.y); v.z = f2bf(f.z); v.w = f2bf(f.w);
        *(ushort4*)((char*)st_a + SWZ(row, (col << 1), 8)) = v;
      }
      // stage x chunk
      #pragma unroll
      for (int e = tid * 4; e < 64 * KCX; e += NTHR * 4) {
        int row = e >> 6, col = e & (KCX - 1);
        float4 f = *(const float4*)(xt + row * (T_ * I_) + kx0 + col);
        ushort4 v;
        v.x = f2bf(f.x); v.y = f2bf(f.y); v.z = f2bf(f.z); v.w = f2bf(f.w);
        *(ushort4*)((char*)st_x + SWZ(row, (col << 1), 7)) = v;
      }
      // stage W chunk (already bf16)
      #pragma unroll
      for (int e = tid * 8; e < 48 * KCX; e += NTHR * 8) {
        int row = e >> 6, col = e & (KCX - 1);
        int g = row >> 4, hi = row & 15;
        uint4 v = *(const uint4*)(wbf + ((g * H_ + h0 + hi) * I_ + kx0 + col));
        *(uint4*)((char*)st_w + SWZ(row, (col << 1), 7)) = v;
      }
      __syncthreads();
      #pragma unroll
      for (int ks = 0; ks < 4; ++ks) {
        const int kb = (ks * 32 + kg * 8) << 1;
        s16x8 a = *(const s16x8*)((char*)st_a + SWZ(bm + ln15, kb, 8));
        s16x8 b0 = *(const s16x8*)((char*)u_lds + SWZ(ln15, ((k0 + ks * 32 + kg * 8) << 1), 11));
        s16x8 b1 = *(const s16x8*)((char*)u_lds + SWZ(16 + ln15, ((k0 + ks * 32 + kg * 8) << 1), 11));
        accz = __builtin_amdgcn_mfma_f32_16x16x32_bf16(a, b0, accz, 0, 0, 0);
        accr = __builtin_amdgcn_mfma_f32_16x16x32_bf16(a, b1, accr, 0, 0, 0);
      }
      #pragma unroll
      for (int ks = 0; ks < 2; ++ks) {
        const int kb = (ks * 32 + kg * 8) << 1;
        s16x8 ax = *(const s16x8*)((char*)st_x + SWZ(bm + ln15, kb, 7));
        s16x8 w0 = *(const s16x8*)((char*)st_w + SWZ(ln15, kb, 7));
        s16x8 w1 = *(const s16x8*)((char*)st_w + SWZ(16 + ln15, kb, 7));
        s16x8 w2 = *(const s16x8*)((char*)st_w + SWZ(32 + ln15, kb, 7));
        apz = __builtin_amdgcn_mfma_f32_16x16x32_bf16(ax, w0, apz, 0, 0, 0);
        apr = __builtin_amdgcn_mfma_f32_16x16x32_bf16(ax, w1, apr, 0, 0, 0);
        aps = __builtin_amdgcn_mfma_f32_16x16x32_bf16(ax, w2, aps, 0, 0, 0);
      }
      __syncthreads();
    }
    // epilogue phase 1: gates z, r; write rs = s*r
    f32x4 zv, sxv, soldv;
    #pragma unroll
    for (int j = 0; j < 4; ++j) {
      int b = bm + (kg << 2) + j;
      float pz = apz[j] + bzv + accz[j];
      float pr = apr[j] + brv + accr[j];
      float z = 1.f / (1.f + __expf(-pz));
      float r = 1.f / (1.f + __expf(-pr));
      float so = scur[b * H_ + h];
      rsb[b * H_ + h] = f2bf(so * r);
      zv[j] = z;
      sxv[j] = aps[j] + bsv;
      soldv[j] = so;
    }
    gbar(cnt, gen);

    // ---------------- phase 2: s_hat GEMM + state update ----------------
    f32x4 accs = {0.f, 0.f, 0.f, 0.f};
    for (int kc = 0; kc < 8; ++kc) {
      const int k0 = kc * KC;
      #pragma unroll
      for (int e = tid * 8; e < 64 * KC; e += NTHR * 8) {
        int row = e >> 7, col = e & (KC - 1);
        uint4 v = *(const uint4*)(rsb + row * H_ + k0 + col);
        *(uint4*)((char*)st_a + SWZ(row, (col << 1), 8)) = v;
      }
      __syncthreads();
      #pragma unroll
      for (int ks = 0; ks < 4; ++ks) {
        const int kb = (ks * 32 + kg * 8) << 1;
        s16x8 a = *(const s16x8*)((char*)st_a + SWZ(bm + ln15, kb, 8));
        s16x8 b2 = *(const s16x8*)((char*)u_lds + SWZ(32 + ln15, ((k0 + ks * 32 + kg * 8) << 1), 11));
        accs = __builtin_amdgcn_mfma_f32_16x16x32_bf16(a, b2, accs, 0, 0, 0);
      }
      __syncthreads();
    }
    #pragma unroll
    for (int j = 0; j < 4; ++j) {
      int b = bm + (kg << 2) + j;
      float shat = fmaxf(accs[j] + sxv[j], 0.f);
      float sn = (1.f - zv[j]) * soldv[j] + zv[j] * shat;
      float m = mask[b * T_ + t];
      float sf = soldv[j] + m * (sn - soldv[j]);
      out[(b * T_ + t) * H_ + h] = sf;
      scur[b * H_ + h] = sf;
    }
    gbar(cnt, gen);
  }
}

extern "C" void kernel_launch(void* const* d_in, const int* in_sizes, int n_in,
                              void* d_out, int out_size, void* d_ws, size_t ws_size,
                              hipStream_t stream) {
  const float* x   = (const float*)d_in[0];
  const float* msk = (const float*)d_in[1];
  const float* s0  = (const float*)d_in[2];
  const float* Ws_ = (const float*)d_in[3];
  const float* Wr_ = (const float*)d_in[4];
  const float* Wz_ = (const float*)d_in[5];
  const float* Us_ = (const float*)d_in[6];
  const float* Ur_ = (const float*)d_in[7];
  const float* Uz_ = (const float*)d_in[8];
  const float* bs_ = (const float*)d_in[9];
  const float* br_ = (const float*)d_in[10];
  const float* bz_ = (const float*)d_in[11];
  float* out = (float*)d_out;
  char* ws = (char*)d_ws;

  (void)hipMemsetAsync(d_ws, 0, 1024, stream);  // barrier counters
  hipLaunchKernelGGL(prep_kernel, dim3(1024), dim3(256), 0, stream,
                     s0, Wz_, Wr_, Ws_, Uz_, Ur_, Us_, ws);

  // Plain launch: 64 blocks, 1 block/CU (126KB LDS) on a 256-CU device are
  // all co-resident by construction; the agent-scope sense-reversing barrier
  // needs no cooperative-launch support (which failed silently last round).
  hipLaunchKernelGGL(scan_kernel, dim3(NBLK), dim3(NTHR), 0, stream,
                     x, msk, bz_, br_, bs_, ws, out);
}

// Round 5
// 11408.389 us; speedup vs baseline: 2.8735x; 2.8735x over previous
//
#include <hip/hip_runtime.h>

typedef unsigned short u16;
typedef unsigned long long u64;
typedef float f32x4 __attribute__((ext_vector_type(4)));
typedef short s16x8 __attribute__((ext_vector_type(8)));

#define B_ 64
#define T_ 512
#define I_ 512
#define H_ 1024
#define NBLK 64
#define NTHR 256
#define WIN 16

// workspace layout (bytes)
#define OFF_CNT 0
#define OFF_GEN 512
#define OFF_SBF 1024                    // s-state bf16, frag layout [4][32][64]x16B = 131072
#define OFF_RS  (OFF_SBF + 131072)      // r*s bf16, frag layout               = 131072
#define OFF_U   (OFF_RS + 131072)       // bf16 U row-major [3][1024][1024]    = 6291456
#define OFF_W   (OFF_U + 6291456)       // bf16 W row-major [3][1024][512]     = 3145728
#define OFF_PJ  (OFF_W + 3145728)       // proj f32 [64 blk][16 t][4 w][3 g][64 lane]x16B = 12582912
// total ~22.3 MB

__device__ __forceinline__ u16 f2bf(float f) {
  unsigned u = __float_as_uint(f);
  return (u16)((u + 0x7FFFu + ((u >> 16) & 1u)) >> 16);
}

union FR { u64 q[2]; s16x8 v; };

__device__ __forceinline__ s16x8 pack8(float4 a, float4 b) {
  s16x8 r;
  r[0] = (short)f2bf(a.x); r[1] = (short)f2bf(a.y);
  r[2] = (short)f2bf(a.z); r[3] = (short)f2bf(a.w);
  r[4] = (short)f2bf(b.x); r[5] = (short)f2bf(b.y);
  r[6] = (short)f2bf(b.z); r[7] = (short)f2bf(b.w);
  return r;
}

__global__ void prep_kernel(const float* __restrict__ s0,
                            const float* __restrict__ Wz, const float* __restrict__ Wr,
                            const float* __restrict__ Ws, const float* __restrict__ Uz,
                            const float* __restrict__ Ur, const float* __restrict__ Us,
                            char* __restrict__ ws) {
  u16* ubf = (u16*)(ws + OFF_U);
  u16* wbf = (u16*)(ws + OFF_W);
  int tid = blockIdx.x * blockDim.x + threadIdx.x;
  int stride = gridDim.x * blockDim.x;
  const int NU = H_ * H_;
  for (int i = tid; i < NU; i += stride) {
    ubf[i] = f2bf(Uz[i]);
    ubf[NU + i] = f2bf(Ur[i]);
    ubf[2 * NU + i] = f2bf(Us[i]);
  }
  const int NW = H_ * I_;
  for (int i = tid; i < NW; i += stride) {
    wbf[i] = f2bf(Wz[i]);
    wbf[NW + i] = f2bf(Wr[i]);
    wbf[2 * NW + i] = f2bf(Ws[i]);
  }
  // s0 -> frag-layout bf16 state: frag[m][kc][lane] 16B; A-frag: row=l&15, k=kc*32+(l>>4)*8
  for (int f = tid; f < 4 * 32 * 64; f += stride) {
    int m = f >> 11, kc = (f >> 6) & 31, l = f & 63;
    int b = m * 16 + (l & 15);
    int k = kc * 32 + (l >> 4) * 8;
    const float* sp = s0 + (u64)b * H_ + k;
    ushort4 lo, hi;
    lo.x = f2bf(sp[0]); lo.y = f2bf(sp[1]); lo.z = f2bf(sp[2]); lo.w = f2bf(sp[3]);
    hi.x = f2bf(sp[4]); hi.y = f2bf(sp[5]); hi.z = f2bf(sp[6]); hi.w = f2bf(sp[7]);
    ushort4* dst = (ushort4*)(ws + OFF_SBF + (u64)f * 16);
    dst[0] = lo; dst[1] = hi;
  }
}

// ---- grid barrier (64 co-resident blocks; shared data travels via sc1 atomics,
// so NO cache-invalidating acquire fence is needed on the consumer side) ----
__device__ __forceinline__ void gbar_arrive(unsigned* cnt, unsigned* gen, unsigned& g) {
  asm volatile("s_waitcnt vmcnt(0)" ::: "memory");  // all sc1 stores visible at MALL
  __syncthreads();
  if (threadIdx.x == 0) {
    g = __hip_atomic_load(gen, __ATOMIC_RELAXED, __HIP_MEMORY_SCOPE_AGENT);
    unsigned a = __hip_atomic_fetch_add(cnt, 1u, __ATOMIC_RELAXED, __HIP_MEMORY_SCOPE_AGENT);
    if (a == (unsigned)(NBLK - 1)) {
      __hip_atomic_store(cnt, 0u, __ATOMIC_RELAXED, __HIP_MEMORY_SCOPE_AGENT);
      __hip_atomic_fetch_add(gen, 1u, __ATOMIC_RELEASE, __HIP_MEMORY_SCOPE_AGENT);
    }
  }
}
__device__ __forceinline__ void gbar_wait(unsigned* gen, unsigned& g) {
  if (threadIdx.x == 0) {
    while (__hip_atomic_load(gen, __ATOMIC_RELAXED, __HIP_MEMORY_SCOPE_AGENT) == g)
      __builtin_amdgcn_s_sleep(2);
  }
  __syncthreads();
}

#define SWZ(row, byteInRow, rowShift) \
  (((((row) << (rowShift)) + (byteInRow))) ^ (((row) & 7) << 4))

__device__ __forceinline__ void window_proj(int t0, int jb, int wave, int lane,
                                            const float* __restrict__ x,
                                            const u16* w_lds, char* __restrict__ ws) {
  const int ln15 = lane & 15, kg = lane >> 4;
  for (int tt = 0; tt < WIN; ++tt) {
    f32x4 ac0 = {0.f,0.f,0.f,0.f}, ac1 = {0.f,0.f,0.f,0.f}, ac2 = {0.f,0.f,0.f,0.f};
    const float* xp0 = x + ((u64)(wave * 16 + ln15) * T_ + (t0 + tt)) * I_ + kg * 8;
    #pragma unroll
    for (int kc = 0; kc < 16; ++kc) {
      float4 xa = *(const float4*)(xp0 + kc * 32);
      float4 xb = *(const float4*)(xp0 + kc * 32 + 4);
      s16x8 a = pack8(xa, xb);
      const int cb = kc * 64 + kg * 16;
      s16x8 b0 = *(const s16x8*)((const char*)w_lds + SWZ(ln15, cb, 10));
      s16x8 b1 = *(const s16x8*)((const char*)w_lds + SWZ(16 + ln15, cb, 10));
      s16x8 b2 = *(const s16x8*)((const char*)w_lds + SWZ(32 + ln15, cb, 10));
      ac0 = __builtin_amdgcn_mfma_f32_16x16x32_bf16(a, b0, ac0, 0, 0, 0);
      ac1 = __builtin_amdgcn_mfma_f32_16x16x32_bf16(a, b1, ac1, 0, 0, 0);
      ac2 = __builtin_amdgcn_mfma_f32_16x16x32_bf16(a, b2, ac2, 0, 0, 0);
    }
    f32x4* pj = (f32x4*)(ws + OFF_PJ + (u64)jb * 196608 + (u64)((tt * 4 + wave) * 3) * 1024 + lane * 16);
    pj[0]   = ac0;   // + g*64 f32x4 per gate
    pj[64]  = ac1;
    pj[128] = ac2;
  }
}

__global__ __launch_bounds__(NTHR, 1) void scan_kernel(
    const float* __restrict__ x, const float* __restrict__ mask,
    const float* __restrict__ bz, const float* __restrict__ br,
    const float* __restrict__ bs, const float* __restrict__ s0,
    char* __restrict__ ws, float* __restrict__ out) {

  __shared__ u16 u_lds[3 * 16 * 1024];   // 96KB  U slices (swizzled, resident all steps)
  __shared__ u16 w_lds[3 * 16 * 512];    // 48KB  W slices (swizzled, resident)
  __shared__ u16 tbf[4][16][16];         // 2KB   per-wave bf16 transpose tile
  __shared__ float tf32[4][16][16];      // 4KB   per-wave f32 transpose tile (out coalescing)

  u64* fsbf = (u64*)(ws + OFF_SBF);
  u64* frs  = (u64*)(ws + OFF_RS);
  const u16* ubf = (const u16*)(ws + OFF_U);
  const u16* wbf = (const u16*)(ws + OFF_W);
  unsigned* cnt = (unsigned*)(ws + OFF_CNT);
  unsigned* gen = (unsigned*)(ws + OFF_GEN);

  const int tid = threadIdx.x;
  const int jb = blockIdx.x;
  const int h0 = jb * 16;
  const int lane = tid & 63;
  const int wave = tid >> 6;
  const int ln15 = lane & 15;
  const int kg = lane >> 4;
  const int h = h0 + ln15;

  // one-time LDS preload of U and W slices (read-only; stays warm: no L2 invalidation anywhere)
  for (int e = tid * 8; e < 3 * 16 * 1024; e += NTHR * 8) {
    int row = e >> 10, k = e & 1023;
    int g = row >> 4, hi = row & 15;
    uint4 v = *(const uint4*)(ubf + ((u64)(g * H_ + h0 + hi) * H_ + k));
    *(uint4*)((char*)u_lds + SWZ(row, (k << 1), 11)) = v;
  }
  for (int e = tid * 8; e < 3 * 16 * 512; e += NTHR * 8) {
    int row = e >> 9, k = e & 511;
    int g = row >> 4, hi = row & 15;
    uint4 v = *(const uint4*)(wbf + ((u64)(g * H_ + h0 + hi) * I_ + k));
    *(uint4*)((char*)w_lds + SWZ(row, (k << 1), 10)) = v;
  }
  const float bzv = bz[h];
  const float brv = br[h];
  const float bsv = bs[h];
  float sreg[4];
  #pragma unroll
  for (int j = 0; j < 4; ++j)
    sreg[j] = s0[(u64)(wave * 16 + kg * 4 + j) * H_ + h];
  __syncthreads();

  unsigned g0 = 0;
  window_proj(0, jb, wave, lane, x, w_lds, ws);

  for (int t = 0; t < T_; ++t) {
    const int tt = t & (WIN - 1);
    // prefetch private per-step data (proj, mask) — L2-warm plain loads
    const f32x4* pjb = (const f32x4*)(ws + OFF_PJ + (u64)jb * 196608 + (u64)((tt * 4 + wave) * 3) * 1024);
    f32x4 p0 = pjb[lane];
    f32x4 p1 = pjb[64 + lane];
    f32x4 p2 = pjb[128 + lane];
    float mv[4];
    #pragma unroll
    for (int j = 0; j < 4; ++j) mv[j] = mask[(u64)(wave * 16 + kg * 4 + j) * T_ + t];

    // ---------- phase 1: z, r ----------
    u64 aS[64];
    {
      const u64* base = fsbf + (u64)(wave * 32) * 128 + lane * 2;
      #pragma unroll
      for (int kc = 0; kc < 32; ++kc) {
        aS[2 * kc]     = __hip_atomic_load(base + kc * 128,     __ATOMIC_RELAXED, __HIP_MEMORY_SCOPE_AGENT);
        aS[2 * kc + 1] = __hip_atomic_load(base + kc * 128 + 1, __ATOMIC_RELAXED, __HIP_MEMORY_SCOPE_AGENT);
      }
    }
    f32x4 accz = {0.f,0.f,0.f,0.f}, accr = {0.f,0.f,0.f,0.f};
    #pragma unroll
    for (int kc = 0; kc < 32; ++kc) {
      FR u; u.q[0] = aS[2 * kc]; u.q[1] = aS[2 * kc + 1];
      const int cb = kc * 64 + kg * 16;
      s16x8 b0 = *(const s16x8*)((const char*)u_lds + SWZ(ln15, cb, 11));
      s16x8 b1 = *(const s16x8*)((const char*)u_lds + SWZ(16 + ln15, cb, 11));
      accz = __builtin_amdgcn_mfma_f32_16x16x32_bf16(u.v, b0, accz, 0, 0, 0);
      accr = __builtin_amdgcn_mfma_f32_16x16x32_bf16(u.v, b1, accr, 0, 0, 0);
    }
    float zv[4];
    #pragma unroll
    for (int j = 0; j < 4; ++j) {
      float z = 1.f / (1.f + __expf(-(accz[j] + p0[j] + bzv)));
      float r = 1.f / (1.f + __expf(-(accr[j] + p1[j] + brv)));
      zv[j] = z;
      tbf[wave][kg * 4 + j][ln15] = f2bf(sreg[j] * r);   // wave-local transpose tile
    }
    if (lane < 32) {  // tile -> frag layout, device-coherent store
      FR u;
      u.v = *(const s16x8*)&tbf[wave][lane & 15][(lane >> 4) * 8];
      u64* dst = frs + ((u64)wave * 32 + (jb >> 1)) * 128 + ((u64)lane + 32 * (jb & 1)) * 2;
      __hip_atomic_store(dst,     u.q[0], __ATOMIC_RELAXED, __HIP_MEMORY_SCOPE_AGENT);
      __hip_atomic_store(dst + 1, u.q[1], __ATOMIC_RELAXED, __HIP_MEMORY_SCOPE_AGENT);
    }
    gbar_arrive(cnt, gen, g0);
    gbar_wait(gen, g0);

    // ---------- phase 2: s_hat, state update ----------
    u64 aR[64];
    {
      const u64* base = frs + (u64)(wave * 32) * 128 + lane * 2;
      #pragma unroll
      for (int kc = 0; kc < 32; ++kc) {
        aR[2 * kc]     = __hip_atomic_load(base + kc * 128,     __ATOMIC_RELAXED, __HIP_MEMORY_SCOPE_AGENT);
        aR[2 * kc + 1] = __hip_atomic_load(base + kc * 128 + 1, __ATOMIC_RELAXED, __HIP_MEMORY_SCOPE_AGENT);
      }
    }
    f32x4 accs = {0.f,0.f,0.f,0.f};
    #pragma unroll
    for (int kc = 0; kc < 32; ++kc) {
      FR u; u.q[0] = aR[2 * kc]; u.q[1] = aR[2 * kc + 1];
      const int cb = kc * 64 + kg * 16;
      s16x8 b2 = *(const s16x8*)((const char*)u_lds + SWZ(32 + ln15, cb, 11));
      accs = __builtin_amdgcn_mfma_f32_16x16x32_bf16(u.v, b2, accs, 0, 0, 0);
    }
    #pragma unroll
    for (int j = 0; j < 4; ++j) {
      float shat = fmaxf(accs[j] + p2[j] + bsv, 0.f);
      float sn = (1.f - zv[j]) * sreg[j] + zv[j] * shat;
      float sf = sreg[j] + mv[j] * (sn - sreg[j]);
      sreg[j] = sf;
      tf32[wave][kg * 4 + j][ln15] = sf;
      tbf[wave][kg * 4 + j][ln15] = f2bf(sf);
    }
    {  // coalesced out store: 16B contiguous in h per (b,t)
      f32x4 o = *(const f32x4*)&tf32[wave][lane >> 2][(lane & 3) * 4];
      f32x4* op = (f32x4*)(out + ((u64)(wave * 16 + (lane >> 2)) * T_ + t) * H_ + h0 + (lane & 3) * 4);
      __builtin_nontemporal_store(o, op);
    }
    if (lane < 32) {  // new state -> frag layout
      FR u;
      u.v = *(const s16x8*)&tbf[wave][lane & 15][(lane >> 4) * 8];
      u64* dst = fsbf + ((u64)wave * 32 + (jb >> 1)) * 128 + ((u64)lane + 32 * (jb & 1)) * 2;
      __hip_atomic_store(dst,     u.q[0], __ATOMIC_RELAXED, __HIP_MEMORY_SCOPE_AGENT);
      __hip_atomic_store(dst + 1, u.q[1], __ATOMIC_RELAXED, __HIP_MEMORY_SCOPE_AGENT);
    }
    gbar_arrive(cnt, gen, g0);
    if (((t + 1) & (WIN - 1)) == 0 && (t + 1) < T_)
      window_proj(t + 1, jb, wave, lane, x, w_lds, ws);  // overlapped with barrier slack
    gbar_wait(gen, g0);
  }
}

extern "C" void kernel_launch(void* const* d_in, const int* in_sizes, int n_in,
                              void* d_out, int out_size, void* d_ws, size_t ws_size,
                              hipStream_t stream) {
  const float* x   = (const float*)d_in[0];
  const float* msk = (const float*)d_in[1];
  const float* s0  = (const float*)d_in[2];
  const float* Ws_ = (const float*)d_in[3];
  const float* Wr_ = (const float*)d_in[4];
  const float* Wz_ = (const float*)d_in[5];
  const float* Us_ = (const float*)d_in[6];
  const float* Ur_ = (const float*)d_in[7];
  const float* Uz_ = (const float*)d_in[8];
  const float* bs_ = (const float*)d_in[9];
  const float* br_ = (const float*)d_in[10];
  const float* bz_ = (const float*)d_in[11];
  float* out = (float*)d_out;
  char* ws = (char*)d_ws;

  (void)hipMemsetAsync(d_ws, 0, 1024, stream);  // barrier counters
  hipLaunchKernelGGL(prep_kernel, dim3(1024), dim3(256), 0, stream,
                     s0, Wz_, Wr_, Ws_, Uz_, Ur_, Us_, ws);
  hipLaunchKernelGGL(scan_kernel, dim3(NBLK), dim3(NTHR), 0, stream,
                     x, msk, bz_, br_, bs_, s0, ws, out);
}